// Round 7
// baseline (189.786 us; speedup 1.0000x reference)
//
#include <hip/hip_runtime.h>
#include <hip/hip_bf16.h>
#include <stdint.h>

#define D_IN 1024
#define NH 16
#define DH 64
#define SEQ 2048
#define BATCH 2

typedef unsigned short u16;
typedef __attribute__((ext_vector_type(8))) short short8;
typedef __attribute__((ext_vector_type(4))) float f32x4;

#define CSCALE 0.1803368801f   // 0.125 * log2(e), folded into Q

__device__ __forceinline__ u16 f2bf(float f) {
    union { float f; uint32_t u; } v; v.f = f;
    uint32_t r = v.u + 0x7FFF + ((v.u >> 16) & 1);
    return (u16)(r >> 16);
}

__device__ __forceinline__ float bf2f(u16 u) {
    union { uint32_t u; float f; } v; v.u = (uint32_t)u << 16;
    return v.f;
}

// pack two fp32 -> two bf16 (truncate) in ONE v_perm_b32
__device__ __forceinline__ uint32_t pktrunc(float a, float b) {
    union { float f; uint32_t u; } x, y;
    x.f = a; y.f = b;
    return __builtin_amdgcn_perm(y.u, x.u, 0x07060302u);
}

__device__ __forceinline__ void async16(const u16* g, u16* l) {
    __builtin_amdgcn_global_load_lds(
        (const __attribute__((address_space(1))) void*)g,
        (__attribute__((address_space(3))) void*)l, 16, 0, 0);
}

// ---- fused prep: x fp32->bf16 cast (blocks 0..4095) + W transpose/cast ----
__global__ __launch_bounds__(256) void prep_kernel(
    const float* __restrict__ x, const float* __restrict__ Wq,
    const float* __restrict__ Wk, const float* __restrict__ Wv,
    u16* __restrict__ xb, u16* __restrict__ WT)
{
    __shared__ float tile[64][65];
    if (blockIdx.x < 4096) {
        int i = (blockIdx.x * 256 + threadIdx.x) * 4;
        float4 v = *(const float4*)(x + i);
        union { u16 u[4]; uint2 d; } o;
        o.u[0] = f2bf(v.x); o.u[1] = f2bf(v.y); o.u[2] = f2bf(v.z); o.u[3] = f2bf(v.w);
        *(uint2*)(xb + i) = o.d;
        return;
    }
    int idx = blockIdx.x - 4096;
    int mat = idx >> 8, rem = idx & 255;
    int k0 = (rem & 15) * 64, n0 = (rem >> 4) * 64;
    const float* W = (mat == 0) ? Wq : (mat == 1 ? Wk : Wv);
    int c = threadIdx.x & 63, rb = threadIdx.x >> 6;
    #pragma unroll
    for (int p = 0; p < 16; ++p) {
        int r = p * 4 + rb;
        tile[r][c] = W[(size_t)(k0 + r) * 1024 + n0 + c];
    }
    __syncthreads();
    #pragma unroll
    for (int p = 0; p < 16; ++p) {
        int r = p * 4 + rb;
        WT[((size_t)mat * 1024 + n0 + r) * 1024 + k0 + c] = f2bf(tile[c][r]);
    }
}

// ---- fused QKV GEMM: 256x256 tile, 8 waves, BK=64, double-buffered LDS,
//      phase-split schedule with counted vmcnt + raw barriers + setprio,
//      chunk-XOR swizzled LDS (conflict-free), XCD-aware block swizzle ----
__global__ __launch_bounds__(512, 2) void qkv_gemm_kernel(
    const u16* __restrict__ xb, const u16* __restrict__ WT,
    const float* __restrict__ bq, const float* __restrict__ bk,
    const float* __restrict__ bv,
    u16* __restrict__ Qb, u16* __restrict__ Kb, u16* __restrict__ Vt)
{
    __shared__ u16 smem[65536];          // 128 KB: As[2][256][64] | Bs[2][256][64]
    u16* As = smem;
    u16* Bs = smem + 32768;

    const int tid  = threadIdx.x;
    const int wave = tid >> 6, lane = tid & 63;
    const int quad = lane >> 4, l15 = lane & 15;
    const int wm = wave >> 2, wn = wave & 3;   // 2 x 4 wave grid, 128x64 per wave
    const int fsig = l15 & 7;

    // XCD-aware swizzle over 192 blocks: XCD x gets 24 contiguous tiles (2 M-rows)
    const int lin = blockIdx.x;
    const int logical = (lin & 7) * 24 + (lin >> 3);
    const int by = logical / 12;          // 0..15 (M)
    const int bx = logical % 12;          // 0..11 (N over 3072)
    const int m0 = by * 256;
    const int n0 = bx * 256;

    const int ch  = tid & 7;              // 16B chunk within 64-elem row
    const int rwT = tid >> 3;             // 0..63 row within 64-row round

    f32x4 acc[8][4];
    #pragma unroll
    for (int i = 0; i < 8; ++i)
        #pragma unroll
        for (int j = 0; j < 4; ++j)
            acc[i][j] = (f32x4){0.f, 0.f, 0.f, 0.f};

    // ---- staging (global_load_lds direct, pre-swizzled global source) ----
    auto stageA = [&](int buf, int kst) {     // 4 loads/thread: rows 0..255
        #pragma unroll
        for (int r = 0; r < 4; ++r) {
            int row = r * 64 + rwT;
            int g = ch ^ (row & 7);
            async16(xb + (size_t)(m0 + row) * 1024 + kst + g * 8,
                    As + buf * 16384 + row * 64 + ch * 8);
        }
    };
    auto stageBh = [&](int buf, int kst, int half) {  // 2 loads/thread: 128 rows
        #pragma unroll
        for (int r = 0; r < 2; ++r) {
            int row = half * 128 + r * 64 + rwT;
            int g = ch ^ (row & 7);
            async16(WT + (size_t)(n0 + row) * 1024 + kst + g * 8,
                    Bs + buf * 16384 + row * 64 + ch * 8);
        }
    };

    // prologue: tile0 -> buf0 (8 loads), tile1 -> buf1 (8 loads)
    stageA(0, 0);  stageBh(0, 0, 0);  stageBh(0, 0, 1);
    stageA(1, 64); stageBh(1, 64, 0); stageBh(1, 64, 1);
    asm volatile("s_waitcnt vmcnt(8)" ::: "memory");   // tile0 landed, tile1 in flight
    __builtin_amdgcn_sched_barrier(0);
    __builtin_amdgcn_s_barrier();

    for (int t = 0; t < 16; ++t) {
        const int cur = t & 1;
        const u16* Ab = As + cur * 16384;
        const u16* Bb = Bs + cur * 16384;
        const bool st = (t + 2 < 16);
        const int k2 = (t + 2) * 64;

        // B fragments for the whole K-tile, read once (consumed every phase)
        short8 bfr[4][2];
        #pragma unroll
        for (int j = 0; j < 4; ++j)
            #pragma unroll
            for (int kk = 0; kk < 2; ++kk)
                bfr[j][kk] = *(const short8*)(Bb + (wn * 64 + j * 16 + l15) * 64 +
                                              (((kk << 2) + quad) ^ fsig) * 8);

        #pragma unroll
        for (int p = 0; p < 4; ++p) {
            // A fragments for this phase's two M-rows
            short8 af[2][2];
            #pragma unroll
            for (int i2 = 0; i2 < 2; ++i2)
                #pragma unroll
                for (int kk = 0; kk < 2; ++kk)
                    af[i2][kk] = *(const short8*)(Ab + (wm * 128 + (p * 2 + i2) * 16 + l15) * 64 +
                                                  (((kk << 2) + quad) ^ fsig) * 8);
            // distributed prefetch of tile t+2 into freed regions of buf[cur]:
            // B half0 after p0-end barrier (all bfr in regs), B half1 next phase
            if (p == 1 && st) stageBh(cur, k2, 0);
            if (p == 2 && st) stageBh(cur, k2, 1);
            __builtin_amdgcn_s_barrier();
            // A overwrite only after every wave has issued all its A ds_reads
            if (p == 3 && st) stageA(cur, k2);
            __builtin_amdgcn_s_setprio(1);
            #pragma unroll
            for (int kk = 0; kk < 2; ++kk)
                #pragma unroll
                for (int i2 = 0; i2 < 2; ++i2)
                    #pragma unroll
                    for (int j = 0; j < 4; ++j)
                        acc[p * 2 + i2][j] = __builtin_amdgcn_mfma_f32_16x16x32_bf16(
                            af[i2][kk], bfr[j][kk], acc[p * 2 + i2][j], 0, 0, 0);
            __builtin_amdgcn_s_setprio(0);
            if (p == 3) {
                // counted drain: wait for tile t+1 only; tile t+2's 8 stay in flight
                if (st)            { asm volatile("s_waitcnt vmcnt(8)" ::: "memory"); }
                else if (t == 14)  { asm volatile("s_waitcnt vmcnt(0)" ::: "memory"); }
                __builtin_amdgcn_sched_barrier(0);
            }
            __builtin_amdgcn_s_barrier();
        }
    }
    __syncthreads();   // full drain before smem reuse by V epilogue

    const int mat = n0 >> 10;
    const int ncb = (n0 & 1023) + wn * 64;   // multiple of 64
    const int hh = ncb >> 6;
    const int bb = m0 >> 11, sb = m0 & 2047;

    if (mat < 2) {
        const float* bias = (mat == 0) ? bq : bk;
        u16* dst = (mat == 0) ? Qb : Kb;
        const float sc = (mat == 0) ? CSCALE : 1.0f;
        #pragma unroll
        for (int i = 0; i < 8; ++i) {
            int ss = sb + wm * 128 + i * 16 + quad * 4;
            #pragma unroll
            for (int j = 0; j < 4; ++j) {
                int dh = j * 16 + l15;
                float bval = bias[ncb + dh];
                size_t base = (((size_t)bb * NH + hh) * SEQ + ss) * DH + dh;
                #pragma unroll
                for (int r = 0; r < 4; ++r)
                    dst[base + (size_t)r * DH] = f2bf((acc[i][j][r] + bval) * sc);
            }
        }
    } else {
        // V: per-wave LDS transpose (smem free after final barrier), two 64-row halves
        u16* vt = smem + wave * (64 * 72);   // [dh][m], stride 72
        u16* vdst = Vt + ((size_t)(bb * NH + hh) * DH) * SEQ;
        #pragma unroll
        for (int h2 = 0; h2 < 2; ++h2) {
            #pragma unroll
            for (int i = 0; i < 4; ++i)
                #pragma unroll
                for (int j = 0; j < 4; ++j) {
                    float bval = bv[ncb + j * 16 + l15];
                    union { u16 u[4]; uint2 d; } o;
                    #pragma unroll
                    for (int r = 0; r < 4; ++r)
                        o.u[r] = f2bf(acc[h2 * 4 + i][j][r] + bval);
                    *(uint2*)(vt + (j * 16 + l15) * 72 + i * 16 + quad * 4) = o.d;
                }
            const int s0w = sb + wm * 128 + h2 * 64;
            #pragma unroll
            for (int it = 0; it < 8; ++it) {
                int dh = it * 8 + (lane >> 3);
                short8 v = *(const short8*)(vt + dh * 72 + (lane & 7) * 8);
                *(short8*)(vdst + (size_t)dh * SEQ + s0w + (lane & 7) * 8) = v;
            }
        }
    }
}

// ---- stage one 64x64 bf16 tile into LDS, swizzle sigma(row)=4*((row>>3)&1)+(row&3) ----
__device__ __forceinline__ void stage64(const u16* g0, size_t gstride, u16* lds,
                                        int wave, int lane)
{
    #pragma unroll
    for (int rnd = 0; rnd < 2; ++rnd) {
        int row = rnd * 32 + wave * 8 + (lane >> 3);
        int sig = ((row >> 3) & 1) * 4 + (row & 3);
        int c = (lane & 7) ^ sig;
        async16(g0 + (size_t)row * gstride + c * 8, lds + row * 64 + (lane & 7) * 8);
    }
}

// ---- flash attention (causal), key-split jobs, in-lane P, DEFERRED-PV (T15):
//      at step t: QK(t) [MFMA] + finish(t-1) [exp/pack/L/PV] — register-independent,
//      so softmax VALU of t-1 fills QK-MFMA shadow of t. K dbuf, V tri-buf (40 KB). ----
__global__ __launch_bounds__(256) void flash_mfma_kernel(
    const u16* __restrict__ Qb, const u16* __restrict__ Kb,
    const u16* __restrict__ Vt, float* __restrict__ out,
    u16* __restrict__ Opart, float* __restrict__ Lpart)
{
    static const int JQT[24] = {7,15,15,14,14, 6,13,13,12,12, 5,11,11,10,10,
                                4, 9, 9, 8, 8, 3, 2, 1, 0};
    static const int JHF[24] = {-1,0,1,0,1, -1,0,1,0,1, -1,0,1,0,1,
                                -1,0,1,0,1, -1,-1,-1,-1};

    __shared__ u16 Ks[2][64 * 64];   // [key][dh], sigma-swizzled chunks (dbuf)
    __shared__ u16 Vs[3][64 * 64];   // [dh][key], sigma-swizzled chunks (tri-buf)

    const int tid  = threadIdx.x;
    const int wave = tid >> 6, lane = tid & 63;
    const int quad = lane >> 4, l15 = lane & 15;
    const int bhx = blockIdx.x;                 // 0..31
    const int b = bhx >> 4, h = bhx & 15;
    const int job = blockIdx.y;                 // 0..23, heaviest-first
    const int qt = JQT[job], hf = JHF[job];
    const int t0 = (hf == 1) ? qt + 1 : 0;
    const int t1 = (hf == 0) ? qt + 1 : 2 * qt + 2;
    const int q0 = qt * 128;
    const int wq0 = wave * 32;
    const size_t bh = (size_t)bhx;
    const u16* Qp = Qb + bh * SEQ * DH;
    const u16* Kp = Kb + bh * SEQ * DH;
    const u16* Vp = Vt + bh * DH * SEQ;

    // Q as B-operand fragments
    short8 qf[2][2];
    #pragma unroll
    for (int qa = 0; qa < 2; ++qa) {
        const u16* qrp = Qp + (size_t)(q0 + wq0 + qa * 16 + l15) * DH;
        qf[qa][0] = *(const short8*)(qrp + quad * 8);
        qf[qa][1] = *(const short8*)(qrp + 32 + quad * 8);
    }

    const short8 ones = (short8){0x3F80, 0x3F80, 0x3F80, 0x3F80,
                                 0x3F80, 0x3F80, 0x3F80, 0x3F80};  // bf16 1.0

    f32x4 O[2][4], L[2];
    #pragma unroll
    for (int pa = 0; pa < 2; ++pa) {
        #pragma unroll
        for (int f = 0; f < 4; ++f) O[pa][f] = (f32x4){0.f, 0.f, 0.f, 0.f};
        L[pa] = (f32x4){0.f, 0.f, 0.f, 0.f};
    }

    const int wqmax = q0 + wq0 + 31;
    const int krbase = (l15 >> 2) * 8 + (l15 & 3);
    const int ksig   = ((l15 >> 2) & 1) * 4 + (l15 & 3);
    const int vsig   = ((l15 >> 3) & 1) * 4 + (l15 & 3);

    // QK^T for tile t into sf (reads Ks[t&1])
    auto qkTile = [&](f32x4 (&sf)[4][2], int t) {
        const u16* kb = Ks[t & 1];
        #pragma unroll
        for (int fj = 0; fj < 4; ++fj) {
            int krow = (fj >> 1) * 32 + krbase + (fj & 1) * 4;
            const u16* kp = kb + krow * 64;
            short8 k0f = *(const short8*)(kp + (quad ^ ksig) * 8);
            short8 k1f = *(const short8*)(kp + ((4 + quad) ^ ksig) * 8);
            #pragma unroll
            for (int qa = 0; qa < 2; ++qa) {
                f32x4 s = (f32x4){0.f, 0.f, 0.f, 0.f};
                s = __builtin_amdgcn_mfma_f32_16x16x32_bf16(k0f, qf[qa][0], s, 0, 0, 0);
                s = __builtin_amdgcn_mfma_f32_16x16x32_bf16(k1f, qf[qa][1], s, 0, 0, 0);
                sf[fj][qa] = s;
            }
        }
    };

    // finish tile tp: exp/mask/pack + L + PV (reads Vs[tp%3])
    auto finishTile = [&](f32x4 (&sf)[4][2], int tp) {
        const int kb0 = tp * 64;
        const bool diag = (kb0 + 63 > q0 + wq0);
        const u16* vbase = Vs[tp % 3];
        short8 pA[2][2];
        #pragma unroll
        for (int qa = 0; qa < 2; ++qa) {
            #pragma unroll
            for (int fj = 0; fj < 4; ++fj)
                #pragma unroll
                for (int r = 0; r < 4; ++r) {
                    float p = __builtin_amdgcn_exp2f(sf[fj][qa][r]);
                    if (diag) {
                        int key = kb0 + (fj >> 1) * 32 + quad * 8 + (fj & 1) * 4 + r;
                        int qg  = q0 + wq0 + qa * 16 + l15;
                        p = (key <= qg) ? p : 0.f;
                    }
                    sf[fj][qa][r] = p;
                }
            union { uint32_t d[4]; short8 v; } a0, a1;
            a0.d[0] = pktrunc(sf[0][qa][0], sf[0][qa][1]);
            a0.d[1] = pktrunc(sf[0][qa][2], sf[0][qa][3]);
            a0.d[2] = pktrunc(sf[1][qa][0], sf[1][qa][1]);
            a0.d[3] = pktrunc(sf[1][qa][2], sf[1][qa][3]);
            a1.d[0] = pktrunc(sf[2][qa][0], sf[2][qa][1]);
            a1.d[1] = pktrunc(sf[2][qa][2], sf[2][qa][3]);
            a1.d[2] = pktrunc(sf[3][qa][0], sf[3][qa][1]);
            a1.d[3] = pktrunc(sf[3][qa][2], sf[3][qa][3]);
            pA[qa][0] = a0.v;
            pA[qa][1] = a1.v;
            L[qa] = __builtin_amdgcn_mfma_f32_16x16x32_bf16(pA[qa][0], ones, L[qa], 0, 0, 0);
            L[qa] = __builtin_amdgcn_mfma_f32_16x16x32_bf16(pA[qa][1], ones, L[qa], 0, 0, 0);
        }
        #pragma unroll
        for (int fo = 0; fo < 4; ++fo) {
            const u16* vrow = vbase + (fo * 16 + l15) * 64;
            short8 vb0 = *(const short8*)(vrow + (quad ^ vsig) * 8);
            short8 vb1 = *(const short8*)(vrow + ((4 + quad) ^ vsig) * 8);
            #pragma unroll
            for (int pa = 0; pa < 2; ++pa) {
                O[pa][fo] = __builtin_amdgcn_mfma_f32_16x16x32_bf16(pA[pa][0], vb0, O[pa][fo], 0, 0, 0);
                O[pa][fo] = __builtin_amdgcn_mfma_f32_16x16x32_bf16(pA[pa][1], vb1, O[pa][fo], 0, 0, 0);
            }
        }
    };

    // prologue: stage tile t0, wait, barrier
    stage64(Kp + (size_t)t0 * 64 * DH, DH, Ks[t0 & 1], wave, lane);
    stage64(Vp + t0 * 64, SEQ, Vs[t0 % 3], wave, lane);
    asm volatile("s_waitcnt vmcnt(0)" ::: "memory");
    __builtin_amdgcn_sched_barrier(0);
    __builtin_amdgcn_s_barrier();

    f32x4 sA[4][2], sB[4][2];
    int tpA = -1, tpB = -1;

    for (int t = t0; t < t1; ++t) {
        const bool st = (t + 1 < t1);
        if (st) {
            int k1 = (t + 1) * 64;
            stage64(Kp + (size_t)k1 * DH, DH, Ks[(t + 1) & 1], wave, lane);
            stage64(Vp + k1, SEQ, Vs[(t + 1) % 3], wave, lane);
        }
        const int k0 = t * 64;
        const bool cmp = (k0 <= wqmax);
        if (((t - t0) & 1) == 0) {
            if (cmp) qkTile(sA, t);            // MFMA, independent of finish below
            if (tpB >= 0) { finishTile(sB, tpB); tpB = -1; }
            if (cmp) tpA = t;
        } else {
            if (cmp) qkTile(sB, t);
            if (tpA >= 0) { finishTile(sA, tpA); tpA = -1; }
            if (cmp) tpB = t;
        }
        if (st) {
            asm volatile("s_waitcnt vmcnt(0)" ::: "memory");
            __builtin_amdgcn_sched_barrier(0);
            __builtin_amdgcn_s_barrier();
        }
    }
    if (tpA >= 0) finishTile(sA, tpA);
    if (tpB >= 0) finishTile(sB, tpB);

    if (hf < 0) {
        #pragma unroll
        for (int pa = 0; pa < 2; ++pa)
            #pragma unroll
            for (int fo = 0; fo < 4; ++fo)
                #pragma unroll
                for (int r = 0; r < 4; ++r) {
                    int s = q0 + wq0 + pa * 16 + quad * 4 + r;
                    out[((size_t)b * SEQ + s) * 1024 + h * DH + fo * 16 + l15] =
                        O[pa][fo][r] / L[pa][r];
                }
    } else {
        const int pi = (qt - 8) * 2 + hf;
        u16* op = Opart + (((size_t)pi * 32 + bhx) * 128) * 64;
        float* lp = Lpart + ((size_t)pi * 32 + bhx) * 128;
        #pragma unroll
        for (int pa = 0; pa < 2; ++pa) {
            #pragma unroll
            for (int fo = 0; fo < 4; ++fo)
                #pragma unroll
                for (int r = 0; r < 4; ++r) {
                    int ql = wq0 + pa * 16 + quad * 4 + r;
                    op[(size_t)ql * 64 + fo * 16 + l15] = f2bf(O[pa][fo][r]);
                }
            if (l15 == 0) {
                #pragma unroll
                for (int r = 0; r < 4; ++r)
                    lp[wq0 + pa * 16 + quad * 4 + r] = L[pa][r];
            }
        }
    }
}

// ---- combine split partials: out = (O0+O1)/(l0+l1) ----
__global__ __launch_bounds__(256) void combine_kernel(
    const u16* __restrict__ Opart, const float* __restrict__ Lpart,
    float* __restrict__ out)
{
    int blk = blockIdx.x;            // 0..255
    int qt = 8 + (blk >> 5);
    int bh = blk & 31;
    int b = bh >> 4, h = bh & 15;
    int pi0 = (qt - 8) * 2, pi1 = pi0 + 1;
    int tid = threadIdx.x;
    int q = tid >> 1, seg = (tid & 1) * 32;
    const u16* o0 = Opart + (((size_t)pi0 * 32 + bh) * 128 + q) * 64 + seg;
    const u16* o1 = Opart + (((size_t)pi1 * 32 + bh) * 128 + q) * 64 + seg;
    float inv = 1.0f / (Lpart[((size_t)pi0 * 32 + bh) * 128 + q] +
                        Lpart[((size_t)pi1 * 32 + bh) * 128 + q]);
    float* op = out + ((size_t)b * SEQ + qt * 128 + q) * 1024 + h * DH + seg;
    #pragma unroll
    for (int d = 0; d < 32; d += 4) {
        union { uint2 d2; u16 u[4]; } a, c;
        a.d2 = *(const uint2*)(o0 + d);
        c.d2 = *(const uint2*)(o1 + d);
        float4 v;
        v.x = (bf2f(a.u[0]) + bf2f(c.u[0])) * inv;
        v.y = (bf2f(a.u[1]) + bf2f(c.u[1])) * inv;
        v.z = (bf2f(a.u[2]) + bf2f(c.u[2])) * inv;
        v.w = (bf2f(a.u[3]) + bf2f(c.u[3])) * inv;
        *(float4*)(op + d) = v;
    }
}

extern "C" void kernel_launch(void* const* d_in, const int* in_sizes, int n_in,
                              void* d_out, int out_size, void* d_ws, size_t ws_size,
                              hipStream_t stream) {
    const float* x  = (const float*)d_in[0];
    const float* Wq = (const float*)d_in[1];
    const float* bq = (const float*)d_in[2];
    const float* Wk = (const float*)d_in[3];
    const float* bk = (const float*)d_in[4];
    const float* Wv = (const float*)d_in[5];
    const float* bv = (const float*)d_in[6];
    float* out = (float*)d_out;

    const size_t NX = (size_t)BATCH * SEQ * D_IN;    // 4M
    const size_t NW = (size_t)3 * D_IN * 1024;       // 3M
    const size_t NP = (size_t)BATCH * NH * SEQ * DH; // 4M
    u16* xb = (u16*)d_ws;
    u16* WT = xb + NX;
    u16* Qb = WT + NW;
    u16* Kb = Qb + NP;
    u16* Vt = Kb + NP;
    // partials alias xb/WT (dead after qkv_gemm): Opart 8 MB, Lpart 256 KB
    u16* Opart = xb;
    float* Lpart = (float*)(xb + NX);    // = WT start

    prep_kernel<<<4096 + 768, 256, 0, stream>>>(x, Wq, Wk, Wv, xb, WT);
    qkv_gemm_kernel<<<dim3(192), 512, 0, stream>>>(xb, WT, bq, bk, bv, Qb, Kb, Vt);
    flash_mfma_kernel<<<dim3(32, 24), 256, 0, stream>>>(Qb, Kb, Vt, out, Opart, Lpart);
    combine_kernel<<<256, 256, 0, stream>>>(Opart, Lpart, out);
}

// Round 8
// 153.990 us; speedup vs baseline: 1.2325x; 1.2325x over previous
//
#include <hip/hip_runtime.h>
#include <hip/hip_bf16.h>
#include <stdint.h>

#define D_IN 1024
#define NH 16
#define DH 64
#define SEQ 2048
#define BATCH 2

typedef unsigned short u16;
typedef __attribute__((ext_vector_type(8))) short short8;
typedef __attribute__((ext_vector_type(4))) float f32x4;

#define CSCALE 0.1803368801f   // 0.125 * log2(e), folded into Q

__device__ __forceinline__ u16 f2bf(float f) {
    union { float f; uint32_t u; } v; v.f = f;
    uint32_t r = v.u + 0x7FFF + ((v.u >> 16) & 1);
    return (u16)(r >> 16);
}

__device__ __forceinline__ float bf2f(u16 u) {
    union { uint32_t u; float f; } v; v.u = (uint32_t)u << 16;
    return v.f;
}

// pack two fp32 -> two bf16 (truncate) in ONE v_perm_b32
__device__ __forceinline__ uint32_t pktrunc(float a, float b) {
    union { float f; uint32_t u; } x, y;
    x.f = a; y.f = b;
    return __builtin_amdgcn_perm(y.u, x.u, 0x07060302u);
}

__device__ __forceinline__ void async16(const u16* g, u16* l) {
    __builtin_amdgcn_global_load_lds(
        (const __attribute__((address_space(1))) void*)g,
        (__attribute__((address_space(3))) void*)l, 16, 0, 0);
}

// ---- fused prep: x fp32->bf16 cast (blocks 0..4095) + W transpose/cast ----
__global__ __launch_bounds__(256) void prep_kernel(
    const float* __restrict__ x, const float* __restrict__ Wq,
    const float* __restrict__ Wk, const float* __restrict__ Wv,
    u16* __restrict__ xb, u16* __restrict__ WT)
{
    __shared__ float tile[64][65];
    if (blockIdx.x < 4096) {
        int i = (blockIdx.x * 256 + threadIdx.x) * 4;
        float4 v = *(const float4*)(x + i);
        union { u16 u[4]; uint2 d; } o;
        o.u[0] = f2bf(v.x); o.u[1] = f2bf(v.y); o.u[2] = f2bf(v.z); o.u[3] = f2bf(v.w);
        *(uint2*)(xb + i) = o.d;
        return;
    }
    int idx = blockIdx.x - 4096;
    int mat = idx >> 8, rem = idx & 255;
    int k0 = (rem & 15) * 64, n0 = (rem >> 4) * 64;
    const float* W = (mat == 0) ? Wq : (mat == 1 ? Wk : Wv);
    int c = threadIdx.x & 63, rb = threadIdx.x >> 6;
    #pragma unroll
    for (int p = 0; p < 16; ++p) {
        int r = p * 4 + rb;
        tile[r][c] = W[(size_t)(k0 + r) * 1024 + n0 + c];
    }
    __syncthreads();
    #pragma unroll
    for (int p = 0; p < 16; ++p) {
        int r = p * 4 + rb;
        WT[((size_t)mat * 1024 + n0 + r) * 1024 + k0 + c] = f2bf(tile[c][r]);
    }
}

// ---- fused QKV GEMM: 256x192 tile, 8 waves, BK=64, double-buffered LDS,
//      grid 16x16 = 256 blocks -> FULL CU coverage (was 192 blocks / 75%).
//      Phase-split schedule with counted vmcnt + raw barriers + setprio,
//      chunk-XOR swizzled LDS (conflict-free), XCD-aware block swizzle.
//      192-wide tiles cross Q/K/V boundaries; every 16-wide j-group is pure
//      (boundaries 1024/2048 are multiples of 16), epilogue dispatches per-j. ----
__global__ __launch_bounds__(512, 2) void qkv_gemm_kernel(
    const u16* __restrict__ xb, const u16* __restrict__ WT,
    const float* __restrict__ bq, const float* __restrict__ bk,
    const float* __restrict__ bv,
    u16* __restrict__ Qb, u16* __restrict__ Kb, u16* __restrict__ Vt)
{
    __shared__ u16 smem[57344];          // 112 KB: As[2][256][64] | Bs[2][192][64]
    u16* As = smem;                      // 2 x 16384
    u16* Bs = smem + 32768;              // 2 x 12288

    const int tid  = threadIdx.x;
    const int wave = tid >> 6, lane = tid & 63;
    const int quad = lane >> 4, l15 = lane & 15;
    const int wm = wave >> 2, wn = wave & 3;   // 2 x 4 wave grid, 128x48 per wave
    const int fsig = l15 & 7;

    // XCD-aware swizzle over 256 blocks: XCD x gets 32 contiguous tiles
    const int lin = blockIdx.x;
    const int logical = (lin & 7) * 32 + (lin >> 3);
    const int by = logical >> 4;          // 0..15 (M)
    const int bx = logical & 15;          // 0..15 (N over 3072)
    const int m0 = by * 256;
    const int n0 = bx * 192;

    const int ch  = tid & 7;              // 16B chunk within 64-elem row
    const int rwT = tid >> 3;             // 0..63 row within 64-row round

    f32x4 acc[8][3];
    #pragma unroll
    for (int i = 0; i < 8; ++i)
        #pragma unroll
        for (int j = 0; j < 3; ++j)
            acc[i][j] = (f32x4){0.f, 0.f, 0.f, 0.f};

    // ---- staging (global_load_lds direct, pre-swizzled global source) ----
    auto stageA = [&](int buf, int kst) {     // 4 loads/thread: rows 0..255
        #pragma unroll
        for (int r = 0; r < 4; ++r) {
            int row = r * 64 + rwT;
            int g = ch ^ (row & 7);
            async16(xb + (size_t)(m0 + row) * 1024 + kst + g * 8,
                    As + buf * 16384 + row * 64 + ch * 8);
        }
    };
    auto stageB1 = [&](int buf, int kst, int r) {  // 1 load/thread: 64 rows
        int row = r * 64 + rwT;
        int g = ch ^ (row & 7);
        async16(WT + (size_t)(n0 + row) * 1024 + kst + g * 8,
                Bs + buf * 12288 + row * 64 + ch * 8);
    };

    // prologue: tile0 (7 loads) -> buf0, tile1 (7 loads) -> buf1
    stageA(0, 0);  stageB1(0, 0, 0);  stageB1(0, 0, 1);  stageB1(0, 0, 2);
    stageA(1, 64); stageB1(1, 64, 0); stageB1(1, 64, 1); stageB1(1, 64, 2);
    asm volatile("s_waitcnt vmcnt(7)" ::: "memory");   // tile0 landed, tile1 in flight
    __builtin_amdgcn_sched_barrier(0);
    __builtin_amdgcn_s_barrier();

    for (int t = 0; t < 16; ++t) {
        const int cur = t & 1;
        const u16* Ab = As + cur * 16384;
        const u16* Bb = Bs + cur * 12288;
        const bool st = (t + 2 < 16);
        const int k2 = (t + 2) * 64;

        // B fragments for the whole K-tile, read once (consumed every phase)
        short8 bfr[3][2];
        #pragma unroll
        for (int j = 0; j < 3; ++j)
            #pragma unroll
            for (int kk = 0; kk < 2; ++kk)
                bfr[j][kk] = *(const short8*)(Bb + (wn * 48 + j * 16 + l15) * 64 +
                                              (((kk << 2) + quad) ^ fsig) * 8);

        #pragma unroll
        for (int p = 0; p < 4; ++p) {
            // A fragments for this phase's two M-rows
            short8 af[2][2];
            #pragma unroll
            for (int i2 = 0; i2 < 2; ++i2)
                #pragma unroll
                for (int kk = 0; kk < 2; ++kk)
                    af[i2][kk] = *(const short8*)(Ab + (wm * 128 + (p * 2 + i2) * 16 + l15) * 64 +
                                                  (((kk << 2) + quad) ^ fsig) * 8);
            // distributed prefetch of tile t+2 into freed regions of buf[cur]:
            // B rounds 0-1 at p1, round 2 at p2 (all bfr in regs after p0);
            // A after p3's barrier (p3's af reads issued pre-barrier)
            if (p == 1 && st) { stageB1(cur, k2, 0); stageB1(cur, k2, 1); }
            if (p == 2 && st) { stageB1(cur, k2, 2); }
            __builtin_amdgcn_s_barrier();
            if (p == 3 && st) stageA(cur, k2);
            __builtin_amdgcn_s_setprio(1);
            #pragma unroll
            for (int kk = 0; kk < 2; ++kk)
                #pragma unroll
                for (int i2 = 0; i2 < 2; ++i2)
                    #pragma unroll
                    for (int j = 0; j < 3; ++j)
                        acc[p * 2 + i2][j] = __builtin_amdgcn_mfma_f32_16x16x32_bf16(
                            af[i2][kk], bfr[j][kk], acc[p * 2 + i2][j], 0, 0, 0);
            __builtin_amdgcn_s_setprio(0);
            if (p == 3) {
                // counted drain: wait tile t+1 only; tile t+2's 7 stay in flight
                if (st)            { asm volatile("s_waitcnt vmcnt(7)" ::: "memory"); }
                else if (t == 14)  { asm volatile("s_waitcnt vmcnt(0)" ::: "memory"); }
                __builtin_amdgcn_sched_barrier(0);
            }
            __builtin_amdgcn_s_barrier();
        }
    }
    __syncthreads();   // full drain before smem reuse by V epilogue

    const int bb = m0 >> 11, sb = m0 & 2047;
    u16* vt = smem + wave * (16 * 136);   // per-wave [16 dh][128 s] scratch, stride 136

    #pragma unroll
    for (int j = 0; j < 3; ++j) {
        const int ncbj = n0 + wn * 48 + j * 16;  // multiple of 16, pure matrix
        const int matj = ncbj >> 10;
        const int cin  = ncbj & 1023;
        const int hh   = cin >> 6;
        const int dh0  = cin & 63;               // multiple of 16
        if (matj < 2) {
            const float* bias = (matj == 0) ? bq : bk;
            u16* dst = (matj == 0) ? Qb : Kb;
            const float sc = (matj == 0) ? CSCALE : 1.0f;
            const float bval = bias[cin + l15];
            #pragma unroll
            for (int i = 0; i < 8; ++i) {
                int ss = sb + wm * 128 + i * 16 + quad * 4;
                size_t base = (((size_t)bb * NH + hh) * SEQ + ss) * DH + dh0 + l15;
                #pragma unroll
                for (int r = 0; r < 4; ++r)
                    dst[base + (size_t)r * DH] = f2bf((acc[i][j][r] + bval) * sc);
            }
        } else {
            // V j-group: 16 dh x 128 s transpose via wave-private LDS scratch
            const float bval = bv[cin + l15];
            #pragma unroll
            for (int i = 0; i < 8; ++i) {
                union { u16 u[4]; uint2 d; } o;
                #pragma unroll
                for (int r = 0; r < 4; ++r)
                    o.u[r] = f2bf(acc[i][j][r] + bval);
                *(uint2*)(vt + l15 * 136 + i * 16 + quad * 4) = o.d;
            }
            u16* vdst = Vt + ((size_t)(bb * NH + hh) * DH + dh0) * SEQ;
            const int s0w = sb + wm * 128;
            const int dh = lane >> 2;            // 0..15
            #pragma unroll
            for (int it = 0; it < 4; ++it) {
                int c0 = (lane & 3) * 32 + it * 8;
                short8 v = *(const short8*)(vt + dh * 136 + c0);
                *(short8*)(vdst + (size_t)dh * SEQ + s0w + c0) = v;
            }
        }
    }
}

// ---- stage one 64x64 bf16 tile into LDS, swizzle sigma(row)=4*((row>>3)&1)+(row&3) ----
__device__ __forceinline__ void stage64(const u16* g0, size_t gstride, u16* lds,
                                        int wave, int lane)
{
    #pragma unroll
    for (int rnd = 0; rnd < 2; ++rnd) {
        int row = rnd * 32 + wave * 8 + (lane >> 3);
        int sig = ((row >> 3) & 1) * 4 + (row & 3);
        int c = (lane & 7) ^ sig;
        async16(g0 + (size_t)row * gstride + c * 8, lds + row * 64 + (lane & 7) * 8);
    }
}

// ---- flash attention (causal), key-split jobs, in-lane P,
//      tri-buffered K/V with counted vmcnt across raw barriers (R4-proven) ----
__global__ __launch_bounds__(256) void flash_mfma_kernel(
    const u16* __restrict__ Qb, const u16* __restrict__ Kb,
    const u16* __restrict__ Vt, float* __restrict__ out,
    u16* __restrict__ Opart, float* __restrict__ Lpart)
{
    static const int JQT[24] = {7,15,15,14,14, 6,13,13,12,12, 5,11,11,10,10,
                                4, 9, 9, 8, 8, 3, 2, 1, 0};
    static const int JHF[24] = {-1,0,1,0,1, -1,0,1,0,1, -1,0,1,0,1,
                                -1,0,1,0,1, -1,-1,-1,-1};

    __shared__ u16 Ks[3][64 * 64];   // [key][dh], sigma-swizzled chunks, tri-buffer
    __shared__ u16 Vs[3][64 * 64];   // [dh][key], sigma-swizzled chunks, tri-buffer

    const int tid  = threadIdx.x;
    const int wave = tid >> 6, lane = tid & 63;
    const int quad = lane >> 4, l15 = lane & 15;
    const int bhx = blockIdx.x;                 // 0..31
    const int b = bhx >> 4, h = bhx & 15;
    const int job = blockIdx.y;                 // 0..23, heaviest-first
    const int qt = JQT[job], hf = JHF[job];
    const int t0 = (hf == 1) ? qt + 1 : 0;
    const int t1 = (hf == 0) ? qt + 1 : 2 * qt + 2;
    const int q0 = qt * 128;
    const int wq0 = wave * 32;
    const size_t bh = (size_t)bhx;
    const u16* Qp = Qb + bh * SEQ * DH;
    const u16* Kp = Kb + bh * SEQ * DH;
    const u16* Vp = Vt + bh * DH * SEQ;

    // Q as B-operand fragments
    short8 qf[2][2];
    #pragma unroll
    for (int qa = 0; qa < 2; ++qa) {
        const u16* qrp = Qp + (size_t)(q0 + wq0 + qa * 16 + l15) * DH;
        qf[qa][0] = *(const short8*)(qrp + quad * 8);
        qf[qa][1] = *(const short8*)(qrp + 32 + quad * 8);
    }

    const short8 ones = (short8){0x3F80, 0x3F80, 0x3F80, 0x3F80,
                                 0x3F80, 0x3F80, 0x3F80, 0x3F80};  // bf16 1.0

    f32x4 O[2][4], L[2];
    #pragma unroll
    for (int pa = 0; pa < 2; ++pa) {
        #pragma unroll
        for (int f = 0; f < 4; ++f) O[pa][f] = (f32x4){0.f, 0.f, 0.f, 0.f};
        L[pa] = (f32x4){0.f, 0.f, 0.f, 0.f};
    }

    const int wqmax = q0 + wq0 + 31;
    const int krbase = (l15 >> 2) * 8 + (l15 & 3);
    const int ksig   = ((l15 >> 2) & 1) * 4 + (l15 & 3);
    const int vsig   = ((l15 >> 3) & 1) * 4 + (l15 & 3);

    // prologue: stage t0 (and t0+1), leave t0+1 in flight behind counted wait
    int cur = t0 % 3;
    stage64(Kp + (size_t)t0 * 64 * DH, DH, Ks[cur], wave, lane);
    stage64(Vp + t0 * 64, SEQ, Vs[cur], wave, lane);
    if (t0 + 1 < t1) {
        int nb = cur + 1; if (nb >= 3) nb -= 3;
        stage64(Kp + (size_t)(t0 + 1) * 64 * DH, DH, Ks[nb], wave, lane);
        stage64(Vp + (t0 + 1) * 64, SEQ, Vs[nb], wave, lane);
        asm volatile("s_waitcnt vmcnt(4)" ::: "memory");
    } else {
        asm volatile("s_waitcnt vmcnt(0)" ::: "memory");
    }
    __builtin_amdgcn_sched_barrier(0);
    __builtin_amdgcn_s_barrier();

    for (int t = t0; t < t1; ++t) {
        const bool st = (t + 2 < t1);
        if (st) {
            int s2 = cur + 2; if (s2 >= 3) s2 -= 3;   // buffer freed after t-1
            int k2 = (t + 2) * 64;
            stage64(Kp + (size_t)k2 * DH, DH, Ks[s2], wave, lane);
            stage64(Vp + k2, SEQ, Vs[s2], wave, lane);
        }
        const int k0 = t * 64;
        if (k0 <= wqmax) {
            // S^T = K Q^T with permuted K rows
            f32x4 sf[4][2];
            __builtin_amdgcn_s_setprio(1);
            #pragma unroll
            for (int fj = 0; fj < 4; ++fj) {
                int krow = (fj >> 1) * 32 + krbase + (fj & 1) * 4;
                const u16* kp = &Ks[cur][krow * 64];
                short8 k0f = *(const short8*)(kp + (quad ^ ksig) * 8);
                short8 k1f = *(const short8*)(kp + ((4 + quad) ^ ksig) * 8);
                #pragma unroll
                for (int qa = 0; qa < 2; ++qa) {
                    f32x4 s = (f32x4){0.f, 0.f, 0.f, 0.f};
                    s = __builtin_amdgcn_mfma_f32_16x16x32_bf16(k0f, qf[qa][0], s, 0, 0, 0);
                    s = __builtin_amdgcn_mfma_f32_16x16x32_bf16(k1f, qf[qa][1], s, 0, 0, 0);
                    sf[fj][qa] = s;
                }
            }
            __builtin_amdgcn_s_setprio(0);
            const bool diag = (k0 + 63 > q0 + wq0);
            short8 pA[2][2];
            #pragma unroll
            for (int qa = 0; qa < 2; ++qa) {
                #pragma unroll
                for (int fj = 0; fj < 4; ++fj)
                    #pragma unroll
                    for (int r = 0; r < 4; ++r) {
                        float p = __builtin_amdgcn_exp2f(sf[fj][qa][r]);
                        if (diag) {
                            int key = k0 + (fj >> 1) * 32 + quad * 8 + (fj & 1) * 4 + r;
                            int qg  = q0 + wq0 + qa * 16 + l15;
                            p = (key <= qg) ? p : 0.f;
                        }
                        sf[fj][qa][r] = p;
                    }
                union { uint32_t d[4]; short8 v; } a0, a1;
                a0.d[0] = pktrunc(sf[0][qa][0], sf[0][qa][1]);
                a0.d[1] = pktrunc(sf[0][qa][2], sf[0][qa][3]);
                a0.d[2] = pktrunc(sf[1][qa][0], sf[1][qa][1]);
                a0.d[3] = pktrunc(sf[1][qa][2], sf[1][qa][3]);
                a1.d[0] = pktrunc(sf[2][qa][0], sf[2][qa][1]);
                a1.d[1] = pktrunc(sf[2][qa][2], sf[2][qa][3]);
                a1.d[2] = pktrunc(sf[3][qa][0], sf[3][qa][1]);
                a1.d[3] = pktrunc(sf[3][qa][2], sf[3][qa][3]);
                pA[qa][0] = a0.v;
                pA[qa][1] = a1.v;
                L[qa] = __builtin_amdgcn_mfma_f32_16x16x32_bf16(pA[qa][0], ones, L[qa], 0, 0, 0);
                L[qa] = __builtin_amdgcn_mfma_f32_16x16x32_bf16(pA[qa][1], ones, L[qa], 0, 0, 0);
            }
            __builtin_amdgcn_s_setprio(1);
            #pragma unroll
            for (int fo = 0; fo < 4; ++fo) {
                const u16* vrow = &Vs[cur][(fo * 16 + l15) * 64];
                short8 vb0 = *(const short8*)(vrow + (quad ^ vsig) * 8);
                short8 vb1 = *(const short8*)(vrow + ((4 + quad) ^ vsig) * 8);
                #pragma unroll
                for (int pa = 0; pa < 2; ++pa) {
                    O[pa][fo] = __builtin_amdgcn_mfma_f32_16x16x32_bf16(pA[pa][0], vb0, O[pa][fo], 0, 0, 0);
                    O[pa][fo] = __builtin_amdgcn_mfma_f32_16x16x32_bf16(pA[pa][1], vb1, O[pa][fo], 0, 0, 0);
                }
            }
            __builtin_amdgcn_s_setprio(0);
        }
        if (t + 1 < t1) {
            // counted drain: t+1 landed, t+2's 4 loads/thread stay in flight
            if (st) { asm volatile("s_waitcnt vmcnt(4)" ::: "memory"); }
            else    { asm volatile("s_waitcnt vmcnt(0)" ::: "memory"); }
            __builtin_amdgcn_sched_barrier(0);
            __builtin_amdgcn_s_barrier();
        }
        cur = (cur + 1 >= 3) ? 0 : cur + 1;
    }

    if (hf < 0) {
        #pragma unroll
        for (int pa = 0; pa < 2; ++pa)
            #pragma unroll
            for (int fo = 0; fo < 4; ++fo)
                #pragma unroll
                for (int r = 0; r < 4; ++r) {
                    int s = q0 + wq0 + pa * 16 + quad * 4 + r;
                    out[((size_t)b * SEQ + s) * 1024 + h * DH + fo * 16 + l15] =
                        O[pa][fo][r] / L[pa][r];
                }
    } else {
        const int pi = (qt - 8) * 2 + hf;
        u16* op = Opart + (((size_t)pi * 32 + bhx) * 128) * 64;
        float* lp = Lpart + ((size_t)pi * 32 + bhx) * 128;
        #pragma unroll
        for (int pa = 0; pa < 2; ++pa) {
            #pragma unroll
            for (int fo = 0; fo < 4; ++fo)
                #pragma unroll
                for (int r = 0; r < 4; ++r) {
                    int ql = wq0 + pa * 16 + quad * 4 + r;
                    op[(size_t)ql * 64 + fo * 16 + l15] = f2bf(O[pa][fo][r]);
                }
            if (l15 == 0) {
                #pragma unroll
                for (int r = 0; r < 4; ++r)
                    lp[wq0 + pa * 16 + quad * 4 + r] = L[pa][r];
            }
        }
    }
}

// ---- combine split partials: out = (O0+O1)/(l0+l1) ----
__global__ __launch_bounds__(256) void combine_kernel(
    const u16* __restrict__ Opart, const float* __restrict__ Lpart,
    float* __restrict__ out)
{
    int blk = blockIdx.x;            // 0..255
    int qt = 8 + (blk >> 5);
    int bh = blk & 31;
    int b = bh >> 4, h = bh & 15;
    int pi0 = (qt - 8) * 2, pi1 = pi0 + 1;
    int tid = threadIdx.x;
    int q = tid >> 1, seg = (tid & 1) * 32;
    const u16* o0 = Opart + (((size_t)pi0 * 32 + bh) * 128 + q) * 64 + seg;
    const u16* o1 = Opart + (((size_t)pi1 * 32 + bh) * 128 + q) * 64 + seg;
    float inv = 1.0f / (Lpart[((size_t)pi0 * 32 + bh) * 128 + q] +
                        Lpart[((size_t)pi1 * 32 + bh) * 128 + q]);
    float* op = out + ((size_t)b * SEQ + qt * 128 + q) * 1024 + h * DH + seg;
    #pragma unroll
    for (int d = 0; d < 32; d += 4) {
        union { uint2 d2; u16 u[4]; } a, c;
        a.d2 = *(const uint2*)(o0 + d);
        c.d2 = *(const uint2*)(o1 + d);
        float4 v;
        v.x = (bf2f(a.u[0]) + bf2f(c.u[0])) * inv;
        v.y = (bf2f(a.u[1]) + bf2f(c.u[1])) * inv;
        v.z = (bf2f(a.u[2]) + bf2f(c.u[2])) * inv;
        v.w = (bf2f(a.u[3]) + bf2f(c.u[3])) * inv;
        *(float4*)(op + d) = v;
    }
}

extern "C" void kernel_launch(void* const* d_in, const int* in_sizes, int n_in,
                              void* d_out, int out_size, void* d_ws, size_t ws_size,
                              hipStream_t stream) {
    const float* x  = (const float*)d_in[0];
    const float* Wq = (const float*)d_in[1];
    const float* bq = (const float*)d_in[2];
    const float* Wk = (const float*)d_in[3];
    const float* bk = (const float*)d_in[4];
    const float* Wv = (const float*)d_in[5];
    const float* bv = (const float*)d_in[6];
    float* out = (float*)d_out;

    const size_t NX = (size_t)BATCH * SEQ * D_IN;    // 4M
    const size_t NW = (size_t)3 * D_IN * 1024;       // 3M
    const size_t NP = (size_t)BATCH * NH * SEQ * DH; // 4M
    u16* xb = (u16*)d_ws;
    u16* WT = xb + NX;
    u16* Qb = WT + NW;
    u16* Kb = Qb + NP;
    u16* Vt = Kb + NP;
    // partials alias xb/WT (dead after qkv_gemm): Opart 8 MB, Lpart 256 KB
    u16* Opart = xb;
    float* Lpart = (float*)(xb + NX);    // = WT start

    prep_kernel<<<4096 + 768, 256, 0, stream>>>(x, Wq, Wk, Wv, xb, WT);
    qkv_gemm_kernel<<<dim3(256), 512, 0, stream>>>(xb, WT, bq, bk, bv, Qb, Kb, Vt);
    flash_mfma_kernel<<<dim3(32, 24), 256, 0, stream>>>(Qb, Kb, Vt, out, Opart, Lpart);
    combine_kernel<<<256, 256, 0, stream>>>(Opart, Lpart, out);
}